// Round 1
// baseline (747.716 us; speedup 1.0000x reference)
//
#include <hip/hip_runtime.h>

#define N_NODES 100000
#define N_EDGES 1600000
#define N_GRAPHS 512
#define FEAT 128
#define EMB 32

// ---------------- CSR construction ----------------

__global__ __launch_bounds__(256) void k_hist(const int* __restrict__ dst,
                                              int* __restrict__ degcnt) {
  int e = blockIdx.x * 256 + threadIdx.x;
  if (e < N_EDGES) atomicAdd(&degcnt[dst[e]], 1);
}

__global__ __launch_bounds__(256) void k_node_init(const int* __restrict__ degcnt,
                                                   const int* __restrict__ batch,
                                                   float* __restrict__ dis,
                                                   int* __restrict__ gcnt) {
  int i = blockIdx.x * 256 + threadIdx.x;
  if (i < N_NODES) {
    dis[i] = rsqrtf((float)degcnt[i] + 1.0f);
    atomicAdd(&gcnt[batch[i]], 1);
  }
}

__global__ __launch_bounds__(256) void k_scanA(const int* __restrict__ degcnt,
                                               int* __restrict__ blocksum) {
  __shared__ int sh[256];
  int t = threadIdx.x;
  int base = blockIdx.x * 1024;
  int s = 0;
#pragma unroll
  for (int j = 0; j < 4; j++) {
    int idx = base + t * 4 + j;
    if (idx < N_NODES) s += degcnt[idx];
  }
  sh[t] = s;
  __syncthreads();
  for (int off = 128; off > 0; off >>= 1) {
    if (t < off) sh[t] += sh[t + off];
    __syncthreads();
  }
  if (t == 0) blocksum[blockIdx.x] = sh[0];
}

__global__ void k_scanB(const int* __restrict__ blocksum, int* __restrict__ blockoff,
                        int* __restrict__ total_out, int nb) {
  if (threadIdx.x == 0 && blockIdx.x == 0) {
    int run = 0;
    for (int i = 0; i < nb; i++) {
      blockoff[i] = run;
      run += blocksum[i];
    }
    total_out[0] = run;  // row_ptr[N] = E
  }
}

__global__ __launch_bounds__(256) void k_scanC(const int* __restrict__ degcnt,
                                               const int* __restrict__ blockoff,
                                               int* __restrict__ row_ptr) {
  __shared__ int sh[256];
  int t = threadIdx.x;
  int base = blockIdx.x * 1024;
  int v[4];
#pragma unroll
  for (int j = 0; j < 4; j++) {
    int idx = base + t * 4 + j;
    v[j] = (idx < N_NODES) ? degcnt[idx] : 0;
  }
  int tsum = v[0] + v[1] + v[2] + v[3];
  sh[t] = tsum;
  __syncthreads();
  for (int off = 1; off < 256; off <<= 1) {
    int add = (t >= off) ? sh[t - off] : 0;
    __syncthreads();
    sh[t] += add;
    __syncthreads();
  }
  int p = sh[t] - tsum + blockoff[blockIdx.x];  // exclusive prefix
#pragma unroll
  for (int j = 0; j < 4; j++) {
    int idx = base + t * 4 + j;
    if (idx < N_NODES) row_ptr[idx] = p;
    p += v[j];
  }
}

__global__ __launch_bounds__(256) void k_fill(const int* __restrict__ src,
                                              const int* __restrict__ dst,
                                              const int* __restrict__ row_ptr,
                                              int* __restrict__ cursor,
                                              int* __restrict__ col) {
  int e = blockIdx.x * 256 + threadIdx.x;
  if (e < N_EDGES) {
    int d = dst[e];
    int p = atomicAdd(&cursor[d], 1);
    col[row_ptr[d] + p] = src[e];
  }
}

// ---------------- GEMMs (pre-scaled by deg_inv_sqrt) ----------------

// hs1[n][c] = dis[n] * sum_k x[n][k] * W1[k][c]     (128 -> 32)
__global__ __launch_bounds__(256) void k_gemm1(const float* __restrict__ x,
                                               const float* __restrict__ W1,
                                               const float* __restrict__ dis,
                                               float* __restrict__ hs1) {
  __shared__ float Wl[FEAT * EMB];  // 16 KB
  int t = threadIdx.x;
  for (int i = t; i < FEAT * EMB; i += 256) Wl[i] = W1[i];
  __syncthreads();
  int row = blockIdx.x * 8 + (t >> 5);
  int c = t & 31;
  const float4* xr = (const float4*)(x + (size_t)row * FEAT);
  float acc = 0.f;
#pragma unroll
  for (int k4 = 0; k4 < FEAT / 4; ++k4) {
    float4 xv = xr[k4];
    acc = fmaf(xv.x, Wl[(k4 * 4 + 0) * EMB + c], acc);
    acc = fmaf(xv.y, Wl[(k4 * 4 + 1) * EMB + c], acc);
    acc = fmaf(xv.z, Wl[(k4 * 4 + 2) * EMB + c], acc);
    acc = fmaf(xv.w, Wl[(k4 * 4 + 3) * EMB + c], acc);
  }
  hs1[row * EMB + c] = acc * dis[row];
}

// hs2[n][c] = dis[n] * sum_k in1[n][k] * W2[k][c]   (32 -> 32)
__global__ __launch_bounds__(256) void k_gemm2(const float* __restrict__ in1,
                                               const float* __restrict__ W2,
                                               const float* __restrict__ dis,
                                               float* __restrict__ hs2) {
  __shared__ float Wl[EMB * EMB];  // 4 KB
  int t = threadIdx.x;
  for (int i = t; i < EMB * EMB; i += 256) Wl[i] = W2[i];
  __syncthreads();
  int row = blockIdx.x * 8 + (t >> 5);
  int c = t & 31;
  const float4* xr = (const float4*)(in1 + (size_t)row * EMB);
  float acc = 0.f;
#pragma unroll
  for (int k4 = 0; k4 < EMB / 4; ++k4) {
    float4 xv = xr[k4];
    acc = fmaf(xv.x, Wl[(k4 * 4 + 0) * EMB + c], acc);
    acc = fmaf(xv.y, Wl[(k4 * 4 + 1) * EMB + c], acc);
    acc = fmaf(xv.z, Wl[(k4 * 4 + 2) * EMB + c], acc);
    acc = fmaf(xv.w, Wl[(k4 * 4 + 3) * EMB + c], acc);
  }
  hs2[row * EMB + c] = acc * dis[row];
}

// ---------------- Aggregation ----------------

// out1[n][c] = relu(dis[n]*(sum_{e in CSR(n)} hs[col[e]][c] + hs[n][c]) + b[c])
__global__ __launch_bounds__(256) void k_agg1(const float* __restrict__ hs,
                                              const int* __restrict__ row_ptr,
                                              const int* __restrict__ col,
                                              const float* __restrict__ dis,
                                              const float* __restrict__ b,
                                              float* __restrict__ out) {
  int t = threadIdx.x;
  int n = blockIdx.x * 8 + (t >> 5);
  int c = t & 31;
  float acc = hs[n * EMB + c];  // self-loop (already dis-scaled)
  int e0 = row_ptr[n], e1 = row_ptr[n + 1];
  int e = e0;
  for (; e + 1 < e1; e += 2) {
    int s0 = col[e], s1 = col[e + 1];
    float a0 = hs[s0 * EMB + c];
    float a1 = hs[s1 * EMB + c];
    acc += a0;
    acc += a1;
  }
  if (e < e1) acc += hs[col[e] * EMB + c];
  out[n * EMB + c] = fmaxf(fmaf(acc, dis[n], b[c]), 0.f);
}

// Layer-2 aggregation fused with pooling head:
// o2 = relu(dis*(sum + self) + b2); partial = o2*Wo[c]; reduce over 32 lanes;
// atomicAdd into per-graph accumulator.
__global__ __launch_bounds__(256) void k_agg2pool(const float* __restrict__ hs,
                                                  const int* __restrict__ row_ptr,
                                                  const int* __restrict__ col,
                                                  const float* __restrict__ dis,
                                                  const float* __restrict__ b2,
                                                  const float* __restrict__ Wo,
                                                  const int* __restrict__ batch,
                                                  float* __restrict__ gacc) {
  int t = threadIdx.x;
  int n = blockIdx.x * 8 + (t >> 5);
  int c = t & 31;
  float acc = hs[n * EMB + c];
  int e0 = row_ptr[n], e1 = row_ptr[n + 1];
  int e = e0;
  for (; e + 1 < e1; e += 2) {
    int s0 = col[e], s1 = col[e + 1];
    float a0 = hs[s0 * EMB + c];
    float a1 = hs[s1 * EMB + c];
    acc += a0;
    acc += a1;
  }
  if (e < e1) acc += hs[col[e] * EMB + c];
  float o = fmaxf(fmaf(acc, dis[n], b2[c]), 0.f);
  float p = o * Wo[c];
#pragma unroll
  for (int off = 16; off > 0; off >>= 1) p += __shfl_down(p, off, 32);
  if (c == 0) atomicAdd(&gacc[batch[n]], p);
}

__global__ void k_finalize(const float* __restrict__ gacc, const int* __restrict__ gcnt,
                           const float* __restrict__ bo, float* __restrict__ out) {
  int g = blockIdx.x * 256 + threadIdx.x;
  if (g < N_GRAPHS) out[g] = gacc[g] / fmaxf((float)gcnt[g], 1.0f) + bo[0];
}

// ---------------- launch ----------------

extern "C" void kernel_launch(void* const* d_in, const int* in_sizes, int n_in,
                              void* d_out, int out_size, void* d_ws, size_t ws_size,
                              hipStream_t stream) {
  const float* x     = (const float*)d_in[0];
  const int*   ei    = (const int*)d_in[1];   // [2, E] row-major: src then dst
  const int*   batch = (const int*)d_in[2];
  const float* W1    = (const float*)d_in[3];
  const float* b1    = (const float*)d_in[4];
  const float* W2    = (const float*)d_in[5];
  const float* b2    = (const float*)d_in[6];
  const float* Wo    = (const float*)d_in[7];
  const float* bo    = (const float*)d_in[8];
  float* out = (float*)d_out;

  const int* src = ei;
  const int* dst = ei + N_EDGES;

  // workspace layout (16B-aligned slices)
  char* w = (char*)d_ws;
  int*   degcnt  = (int*)w;    w += (size_t)N_NODES * 4;       // zeroed
  int*   cursor  = (int*)w;    w += (size_t)N_NODES * 4;       // zeroed
  float* gacc    = (float*)w;  w += (size_t)N_GRAPHS * 4;      // zeroed
  int*   gcnt    = (int*)w;    w += (size_t)N_GRAPHS * 4;      // zeroed
  size_t zero_bytes = (size_t)(w - (char*)d_ws);               // 804096
  int*   row_ptr = (int*)w;    w += (size_t)(N_NODES + 4) * 4; // N+1 used, padded
  int*   blocksum= (int*)w;    w += 128 * 4;
  int*   blockoff= (int*)w;    w += 128 * 4;
  int*   col     = (int*)w;    w += (size_t)N_EDGES * 4;
  float* dis     = (float*)w;  w += (size_t)N_NODES * 4;
  float* hs1     = (float*)w;  w += (size_t)N_NODES * EMB * 4;
  float* out1    = (float*)w;  w += (size_t)N_NODES * EMB * 4;
  float* hs2     = hs1;  // hs1 dead after agg1; reuse

  const int EB = (N_EDGES + 255) / 256;    // 6250
  const int NB = (N_NODES + 255) / 256;    // 391
  const int SB = (N_NODES + 1023) / 1024;  // 98
  const int RB = N_NODES / 8;              // 12500 (exact)

  hipMemsetAsync(d_ws, 0, zero_bytes, stream);

  k_hist<<<EB, 256, 0, stream>>>(dst, degcnt);
  k_node_init<<<NB, 256, 0, stream>>>(degcnt, batch, dis, gcnt);
  k_scanA<<<SB, 256, 0, stream>>>(degcnt, blocksum);
  k_scanB<<<1, 64, 0, stream>>>(blocksum, blockoff, row_ptr + N_NODES, SB);
  k_scanC<<<SB, 256, 0, stream>>>(degcnt, blockoff, row_ptr);
  k_fill<<<EB, 256, 0, stream>>>(src, dst, row_ptr, cursor, col);

  k_gemm1<<<RB, 256, 0, stream>>>(x, W1, dis, hs1);
  k_agg1<<<RB, 256, 0, stream>>>(hs1, row_ptr, col, dis, b1, out1);
  k_gemm2<<<RB, 256, 0, stream>>>(out1, W2, dis, hs2);
  k_agg2pool<<<RB, 256, 0, stream>>>(hs2, row_ptr, col, dis, b2, Wo, batch, gacc);
  k_finalize<<<2, 256, 0, stream>>>(gacc, gcnt, bo, out);
}

// Round 2
// 728.140 us; speedup vs baseline: 1.0269x; 1.0269x over previous
//
#include <hip/hip_runtime.h>

#define N_NODES 100000
#define N_EDGES 1600000
#define N_GRAPHS 512
#define FEAT 128
#define EMB 32
#define ZROW N_NODES                        // dedicated zero row for padding
#define PADCAP (N_EDGES + 8 * N_NODES)      // 2.4M worst-case padded col slots

__device__ __forceinline__ int pad8(int d) { return (d + 7) & ~7; }

// ---------------- CSR construction ----------------

__global__ __launch_bounds__(256) void k_hist(const int* __restrict__ dst,
                                              int* __restrict__ degcnt) {
  int e = blockIdx.x * 256 + threadIdx.x;
  if (e < N_EDGES) atomicAdd(&degcnt[dst[e]], 1);
}

__global__ __launch_bounds__(256) void k_node_init(const int* __restrict__ degcnt,
                                                   const int* __restrict__ batch,
                                                   float* __restrict__ dis,
                                                   int* __restrict__ gcnt) {
  int i = blockIdx.x * 256 + threadIdx.x;
  if (i < N_NODES) {
    dis[i] = rsqrtf((float)degcnt[i] + 1.0f);
    atomicAdd(&gcnt[batch[i]], 1);
  }
}

// fill padded col slots with ZROW; zero the hs zero-row
__global__ __launch_bounds__(256) void k_colfill(int* __restrict__ col,
                                                 float* __restrict__ hs1) {
  int i = blockIdx.x * 256 + threadIdx.x;
  if (i < PADCAP) col[i] = ZROW;
  if (i < EMB) hs1[(size_t)ZROW * EMB + i] = 0.f;
}

__global__ __launch_bounds__(256) void k_scanA(const int* __restrict__ degcnt,
                                               int* __restrict__ blocksum) {
  __shared__ int sh[256];
  int t = threadIdx.x;
  int base = blockIdx.x * 1024;
  int s = 0;
#pragma unroll
  for (int j = 0; j < 4; j++) {
    int idx = base + t * 4 + j;
    if (idx < N_NODES) s += pad8(degcnt[idx]);
  }
  sh[t] = s;
  __syncthreads();
  for (int off = 128; off > 0; off >>= 1) {
    if (t < off) sh[t] += sh[t + off];
    __syncthreads();
  }
  if (t == 0) blocksum[blockIdx.x] = sh[0];
}

__global__ void k_scanB(const int* __restrict__ blocksum, int* __restrict__ blockoff,
                        int* __restrict__ total_out, int nb) {
  if (threadIdx.x == 0 && blockIdx.x == 0) {
    int run = 0;
    for (int i = 0; i < nb; i++) {
      blockoff[i] = run;
      run += blocksum[i];
    }
    total_out[0] = run;  // row_ptr[N] = padded E
  }
}

__global__ __launch_bounds__(256) void k_scanC(const int* __restrict__ degcnt,
                                               const int* __restrict__ blockoff,
                                               int* __restrict__ row_ptr) {
  __shared__ int sh[256];
  int t = threadIdx.x;
  int base = blockIdx.x * 1024;
  int v[4];
#pragma unroll
  for (int j = 0; j < 4; j++) {
    int idx = base + t * 4 + j;
    v[j] = (idx < N_NODES) ? pad8(degcnt[idx]) : 0;
  }
  int tsum = v[0] + v[1] + v[2] + v[3];
  sh[t] = tsum;
  __syncthreads();
  for (int off = 1; off < 256; off <<= 1) {
    int add = (t >= off) ? sh[t - off] : 0;
    __syncthreads();
    sh[t] += add;
    __syncthreads();
  }
  int p = sh[t] - tsum + blockoff[blockIdx.x];  // exclusive prefix
#pragma unroll
  for (int j = 0; j < 4; j++) {
    int idx = base + t * 4 + j;
    if (idx < N_NODES) row_ptr[idx] = p;
    p += v[j];
  }
}

__global__ __launch_bounds__(256) void k_fill(const int* __restrict__ src,
                                              const int* __restrict__ dst,
                                              const int* __restrict__ row_ptr,
                                              int* __restrict__ cursor,
                                              int* __restrict__ col) {
  int e = blockIdx.x * 256 + threadIdx.x;
  if (e < N_EDGES) {
    int d = dst[e];
    int p = atomicAdd(&cursor[d], 1);
    col[row_ptr[d] + p] = src[e];
  }
}

// ---------------- GEMMs (pre-scaled by deg_inv_sqrt) ----------------

__global__ __launch_bounds__(256) void k_gemm1(const float* __restrict__ x,
                                               const float* __restrict__ W1,
                                               const float* __restrict__ dis,
                                               float* __restrict__ hs1) {
  __shared__ float Wl[FEAT * EMB];  // 16 KB
  int t = threadIdx.x;
  for (int i = t; i < FEAT * EMB; i += 256) Wl[i] = W1[i];
  __syncthreads();
  int row = blockIdx.x * 8 + (t >> 5);
  int c = t & 31;
  const float4* xr = (const float4*)(x + (size_t)row * FEAT);
  float acc = 0.f;
#pragma unroll
  for (int k4 = 0; k4 < FEAT / 4; ++k4) {
    float4 xv = xr[k4];
    acc = fmaf(xv.x, Wl[(k4 * 4 + 0) * EMB + c], acc);
    acc = fmaf(xv.y, Wl[(k4 * 4 + 1) * EMB + c], acc);
    acc = fmaf(xv.z, Wl[(k4 * 4 + 2) * EMB + c], acc);
    acc = fmaf(xv.w, Wl[(k4 * 4 + 3) * EMB + c], acc);
  }
  hs1[row * EMB + c] = acc * dis[row];
}

__global__ __launch_bounds__(256) void k_gemm2(const float* __restrict__ in1,
                                               const float* __restrict__ W2,
                                               const float* __restrict__ dis,
                                               float* __restrict__ hs2) {
  __shared__ float Wl[EMB * EMB];  // 4 KB
  int t = threadIdx.x;
  for (int i = t; i < EMB * EMB; i += 256) Wl[i] = W2[i];
  __syncthreads();
  int row = blockIdx.x * 8 + (t >> 5);
  int c = t & 31;
  const float4* xr = (const float4*)(in1 + (size_t)row * EMB);
  float acc = 0.f;
#pragma unroll
  for (int k4 = 0; k4 < EMB / 4; ++k4) {
    float4 xv = xr[k4];
    acc = fmaf(xv.x, Wl[(k4 * 4 + 0) * EMB + c], acc);
    acc = fmaf(xv.y, Wl[(k4 * 4 + 1) * EMB + c], acc);
    acc = fmaf(xv.z, Wl[(k4 * 4 + 2) * EMB + c], acc);
    acc = fmaf(xv.w, Wl[(k4 * 4 + 3) * EMB + c], acc);
  }
  hs2[row * EMB + c] = acc * dis[row];
}

// ---------------- Aggregation (deep-MLP gather, 8 edges per chunk) ----------------

// acc[n][c] = self + sum over padded CSR row (pads hit the zero row)
__device__ __forceinline__ float agg_row(const float* __restrict__ hs,
                                         const int* __restrict__ row_ptr,
                                         const int* __restrict__ col,
                                         int n, int c) {
  float acc = hs[n * EMB + c];  // self-loop (already dis-scaled)
  int e0 = row_ptr[n], e1 = row_ptr[n + 1];  // e1-e0 multiple of 8
  int lo = c & 7;
  int s = 0;
  if (e0 < e1) s = col[e0 + lo];  // lanes 0..7 hold 8 consecutive indices
  for (int e = e0; e < e1; e += 8) {
    int sn = 0;
    if (e + 8 < e1) sn = col[e + 8 + lo];  // prefetch next chunk's indices
    int s0 = __shfl(s, 0, 32), s1 = __shfl(s, 1, 32);
    int s2 = __shfl(s, 2, 32), s3 = __shfl(s, 3, 32);
    int s4 = __shfl(s, 4, 32), s5 = __shfl(s, 5, 32);
    int s6 = __shfl(s, 6, 32), s7 = __shfl(s, 7, 32);
    float v0 = hs[s0 * EMB + c];
    float v1 = hs[s1 * EMB + c];
    float v2 = hs[s2 * EMB + c];
    float v3 = hs[s3 * EMB + c];
    float v4 = hs[s4 * EMB + c];
    float v5 = hs[s5 * EMB + c];
    float v6 = hs[s6 * EMB + c];
    float v7 = hs[s7 * EMB + c];
    acc += ((v0 + v1) + (v2 + v3)) + ((v4 + v5) + (v6 + v7));
    s = sn;
  }
  return acc;
}

__global__ __launch_bounds__(256) void k_agg1(const float* __restrict__ hs,
                                              const int* __restrict__ row_ptr,
                                              const int* __restrict__ col,
                                              const float* __restrict__ dis,
                                              const float* __restrict__ b,
                                              float* __restrict__ out) {
  int t = threadIdx.x;
  int n = blockIdx.x * 8 + (t >> 5);
  int c = t & 31;
  float acc = agg_row(hs, row_ptr, col, n, c);
  out[n * EMB + c] = fmaxf(fmaf(acc, dis[n], b[c]), 0.f);
}

__global__ __launch_bounds__(256) void k_agg2pool(const float* __restrict__ hs,
                                                  const int* __restrict__ row_ptr,
                                                  const int* __restrict__ col,
                                                  const float* __restrict__ dis,
                                                  const float* __restrict__ b2,
                                                  const float* __restrict__ Wo,
                                                  const int* __restrict__ batch,
                                                  float* __restrict__ gacc) {
  int t = threadIdx.x;
  int n = blockIdx.x * 8 + (t >> 5);
  int c = t & 31;
  float acc = agg_row(hs, row_ptr, col, n, c);
  float o = fmaxf(fmaf(acc, dis[n], b2[c]), 0.f);
  float p = o * Wo[c];
#pragma unroll
  for (int off = 16; off > 0; off >>= 1) p += __shfl_down(p, off, 32);
  if (c == 0) atomicAdd(&gacc[batch[n]], p);
}

__global__ void k_finalize(const float* __restrict__ gacc, const int* __restrict__ gcnt,
                           const float* __restrict__ bo, float* __restrict__ out) {
  int g = blockIdx.x * 256 + threadIdx.x;
  if (g < N_GRAPHS) out[g] = gacc[g] / fmaxf((float)gcnt[g], 1.0f) + bo[0];
}

// ---------------- launch ----------------

extern "C" void kernel_launch(void* const* d_in, const int* in_sizes, int n_in,
                              void* d_out, int out_size, void* d_ws, size_t ws_size,
                              hipStream_t stream) {
  const float* x     = (const float*)d_in[0];
  const int*   ei    = (const int*)d_in[1];   // [2, E]: src then dst
  const int*   batch = (const int*)d_in[2];
  const float* W1    = (const float*)d_in[3];
  const float* b1    = (const float*)d_in[4];
  const float* W2    = (const float*)d_in[5];
  const float* b2    = (const float*)d_in[6];
  const float* Wo    = (const float*)d_in[7];
  const float* bo    = (const float*)d_in[8];
  float* out = (float*)d_out;

  const int* src = ei;
  const int* dst = ei + N_EDGES;

  char* w = (char*)d_ws;
  int*   degcnt  = (int*)w;    w += (size_t)N_NODES * 4;       // zeroed
  int*   cursor  = (int*)w;    w += (size_t)N_NODES * 4;       // zeroed
  float* gacc    = (float*)w;  w += (size_t)N_GRAPHS * 4;      // zeroed
  int*   gcnt    = (int*)w;    w += (size_t)N_GRAPHS * 4;      // zeroed
  size_t zero_bytes = (size_t)(w - (char*)d_ws);
  int*   row_ptr = (int*)w;    w += (size_t)(N_NODES + 4) * 4;
  int*   blocksum= (int*)w;    w += 128 * 4;
  int*   blockoff= (int*)w;    w += 128 * 4;
  int*   col     = (int*)w;    w += (size_t)PADCAP * 4;
  float* dis     = (float*)w;  w += (size_t)N_NODES * 4;
  float* hs1     = (float*)w;  w += (size_t)(N_NODES + 1) * EMB * 4;  // +1 zero row
  float* out1    = (float*)w;  w += (size_t)N_NODES * EMB * 4;
  float* hs2     = hs1;  // hs1 dead after agg1; gemm2 leaves zero row intact

  const int EB = (N_EDGES + 255) / 256;    // 6250
  const int NB = (N_NODES + 255) / 256;    // 391
  const int SB = (N_NODES + 1023) / 1024;  // 98
  const int RB = N_NODES / 8;              // 12500 (exact)
  const int CB = (PADCAP + 255) / 256;     // 9375

  hipMemsetAsync(d_ws, 0, zero_bytes, stream);

  k_hist<<<EB, 256, 0, stream>>>(dst, degcnt);
  k_node_init<<<NB, 256, 0, stream>>>(degcnt, batch, dis, gcnt);
  k_colfill<<<CB, 256, 0, stream>>>(col, hs1);
  k_scanA<<<SB, 256, 0, stream>>>(degcnt, blocksum);
  k_scanB<<<1, 64, 0, stream>>>(blocksum, blockoff, row_ptr + N_NODES, SB);
  k_scanC<<<SB, 256, 0, stream>>>(degcnt, blockoff, row_ptr);
  k_fill<<<EB, 256, 0, stream>>>(src, dst, row_ptr, cursor, col);

  k_gemm1<<<RB, 256, 0, stream>>>(x, W1, dis, hs1);
  k_agg1<<<RB, 256, 0, stream>>>(hs1, row_ptr, col, dis, b1, out1);
  k_gemm2<<<RB, 256, 0, stream>>>(out1, W2, dis, hs2);
  k_agg2pool<<<RB, 256, 0, stream>>>(hs2, row_ptr, col, dis, b2, Wo, batch, gacc);
  k_finalize<<<2, 256, 0, stream>>>(gacc, gcnt, bo, out);
}

// Round 3
// 688.783 us; speedup vs baseline: 1.0856x; 1.0571x over previous
//
#include <hip/hip_runtime.h>
#include <hip/hip_fp16.h>

#define N_NODES 100000
#define N_EDGES 1600000
#define N_GRAPHS 512
#define FEAT 128
#define EMB 32
#define ZROW N_NODES                        // dedicated zero row for padding
#define PADCAP (N_EDGES + 8 * N_NODES)      // worst-case padded col slots

typedef unsigned short u16;

__device__ __forceinline__ int pad8(int d) { return (d + 7) & ~7; }

__device__ __forceinline__ float4 h4_to_f4(ushort4 v) {
  union { ushort2 u; __half2 h; } a, b;
  a.u = make_ushort2(v.x, v.y);
  b.u = make_ushort2(v.z, v.w);
  float2 f0 = __half22float2(a.h);
  float2 f1 = __half22float2(b.h);
  return make_float4(f0.x, f0.y, f1.x, f1.y);
}

__device__ __forceinline__ ushort4 f4_to_h4(float4 f) {
  union { ushort2 u; __half2 h; } a, b;
  a.h = __float22half2_rn(make_float2(f.x, f.y));
  b.h = __float22half2_rn(make_float2(f.z, f.w));
  return make_ushort4(a.u.x, a.u.y, b.u.x, b.u.y);
}

// ---------------- CSR construction ----------------

__global__ __launch_bounds__(256) void k_hist(const int* __restrict__ dst,
                                              int* __restrict__ degcnt) {
  int e = blockIdx.x * 256 + threadIdx.x;
  if (e < N_EDGES) atomicAdd(&degcnt[dst[e]], 1);
}

__global__ __launch_bounds__(256) void k_node_init(const int* __restrict__ degcnt,
                                                   const int* __restrict__ batch,
                                                   float* __restrict__ dis,
                                                   int* __restrict__ gcnt) {
  int i = blockIdx.x * 256 + threadIdx.x;
  if (i < N_NODES) {
    dis[i] = rsqrtf((float)degcnt[i] + 1.0f);
    atomicAdd(&gcnt[batch[i]], 1);
  }
}

// fill padded col slots with ZROW; zero the fp16 zero-row of hs1
__global__ __launch_bounds__(256) void k_colfill(int* __restrict__ col,
                                                 u16* __restrict__ hs1) {
  int i = blockIdx.x * 256 + threadIdx.x;
  if (i < PADCAP) col[i] = ZROW;
  if (i < EMB) hs1[(size_t)ZROW * EMB + i] = 0;
}

__global__ __launch_bounds__(256) void k_scanA(const int* __restrict__ degcnt,
                                               int* __restrict__ blocksum) {
  __shared__ int sh[256];
  int t = threadIdx.x;
  int base = blockIdx.x * 1024;
  int s = 0;
#pragma unroll
  for (int j = 0; j < 4; j++) {
    int idx = base + t * 4 + j;
    if (idx < N_NODES) s += pad8(degcnt[idx]);
  }
  sh[t] = s;
  __syncthreads();
  for (int off = 128; off > 0; off >>= 1) {
    if (t < off) sh[t] += sh[t + off];
    __syncthreads();
  }
  if (t == 0) blocksum[blockIdx.x] = sh[0];
}

__global__ void k_scanB(const int* __restrict__ blocksum, int* __restrict__ blockoff,
                        int* __restrict__ total_out, int nb) {
  if (threadIdx.x == 0 && blockIdx.x == 0) {
    int run = 0;
    for (int i = 0; i < nb; i++) {
      blockoff[i] = run;
      run += blocksum[i];
    }
    total_out[0] = run;
  }
}

__global__ __launch_bounds__(256) void k_scanC(const int* __restrict__ degcnt,
                                               const int* __restrict__ blockoff,
                                               int* __restrict__ row_ptr) {
  __shared__ int sh[256];
  int t = threadIdx.x;
  int base = blockIdx.x * 1024;
  int v[4];
#pragma unroll
  for (int j = 0; j < 4; j++) {
    int idx = base + t * 4 + j;
    v[j] = (idx < N_NODES) ? pad8(degcnt[idx]) : 0;
  }
  int tsum = v[0] + v[1] + v[2] + v[3];
  sh[t] = tsum;
  __syncthreads();
  for (int off = 1; off < 256; off <<= 1) {
    int add = (t >= off) ? sh[t - off] : 0;
    __syncthreads();
    sh[t] += add;
    __syncthreads();
  }
  int p = sh[t] - tsum + blockoff[blockIdx.x];
#pragma unroll
  for (int j = 0; j < 4; j++) {
    int idx = base + t * 4 + j;
    if (idx < N_NODES) row_ptr[idx] = p;
    p += v[j];
  }
}

__global__ __launch_bounds__(256) void k_fill(const int* __restrict__ src,
                                              const int* __restrict__ dst,
                                              const int* __restrict__ row_ptr,
                                              int* __restrict__ cursor,
                                              int* __restrict__ col) {
  int e = blockIdx.x * 256 + threadIdx.x;
  if (e < N_EDGES) {
    int d = dst[e];
    int p = atomicAdd(&cursor[d], 1);
    col[row_ptr[d] + p] = src[e];
  }
}

// ---------------- GEMMs (pre-scaled by deg_inv_sqrt, fp16 output) ----------------

__global__ __launch_bounds__(256) void k_gemm1(const float* __restrict__ x,
                                               const float* __restrict__ W1,
                                               const float* __restrict__ dis,
                                               u16* __restrict__ hs1) {
  __shared__ float Wl[FEAT * EMB];  // 16 KB
  int t = threadIdx.x;
  for (int i = t; i < FEAT * EMB; i += 256) Wl[i] = W1[i];
  __syncthreads();
  int row = blockIdx.x * 8 + (t >> 5);
  int c = t & 31;
  const float4* xr = (const float4*)(x + (size_t)row * FEAT);
  float acc = 0.f;
#pragma unroll
  for (int k4 = 0; k4 < FEAT / 4; ++k4) {
    float4 xv = xr[k4];
    acc = fmaf(xv.x, Wl[(k4 * 4 + 0) * EMB + c], acc);
    acc = fmaf(xv.y, Wl[(k4 * 4 + 1) * EMB + c], acc);
    acc = fmaf(xv.z, Wl[(k4 * 4 + 2) * EMB + c], acc);
    acc = fmaf(xv.w, Wl[(k4 * 4 + 3) * EMB + c], acc);
  }
  hs1[row * EMB + c] = __half_as_ushort(__float2half_rn(acc * dis[row]));
}

// hs2[n][c] = dis[n] * sum_k out1[n][k] * W2[k][c]   (fp16 in, fp16 out)
__global__ __launch_bounds__(256) void k_gemm2(const u16* __restrict__ in1,
                                               const float* __restrict__ W2,
                                               const float* __restrict__ dis,
                                               u16* __restrict__ hs2) {
  __shared__ float Wl[EMB * EMB];  // 4 KB
  int t = threadIdx.x;
  for (int i = t; i < EMB * EMB; i += 256) Wl[i] = W2[i];
  __syncthreads();
  int row = blockIdx.x * 8 + (t >> 5);
  int c = t & 31;
  const ushort4* xr = (const ushort4*)(in1 + (size_t)row * EMB);
  float acc = 0.f;
#pragma unroll
  for (int q = 0; q < 8; ++q) {
    float4 xv = h4_to_f4(xr[q]);
    acc = fmaf(xv.x, Wl[(q * 4 + 0) * EMB + c], acc);
    acc = fmaf(xv.y, Wl[(q * 4 + 1) * EMB + c], acc);
    acc = fmaf(xv.z, Wl[(q * 4 + 2) * EMB + c], acc);
    acc = fmaf(xv.w, Wl[(q * 4 + 3) * EMB + c], acc);
  }
  hs2[row * EMB + c] = __half_as_ushort(__float2half_rn(acc * dis[row]));
}

// ---------------- Aggregation: wave-per-node, 8 rows per gather instruction ----------------

// Returns per-lane float4 = full aggregated quad (channels [4*sub,4*sub+4)),
// identical across the 8 edge-slot groups after reduction; self-loop included.
__device__ __forceinline__ float4 agg_row_wide(const u16* __restrict__ hs,
                                               const int* __restrict__ row_ptr,
                                               const int* __restrict__ col,
                                               int n, int g, int sub) {
  const ushort4* hs4 = (const ushort4*)hs;
  int e0 = row_ptr[n], e1 = row_ptr[n + 1];   // multiple of 8 apart
  int nch = (e1 - e0) >> 3;
  int ec = e0 + g;
  float4 acc = make_float4(0.f, 0.f, 0.f, 0.f);
  int s0 = (nch > 0) ? col[ec] : ZROW;
  int s1 = (nch > 1) ? col[ec + 8] : ZROW;
  int i = 0;
  for (; i + 2 <= nch; i += 2) {
    ushort4 va = hs4[s0 * 8 + sub];
    ushort4 vb = hs4[s1 * 8 + sub];
    int t0 = (i + 2 < nch) ? col[ec + (i + 2) * 8] : ZROW;
    int t1 = (i + 3 < nch) ? col[ec + (i + 3) * 8] : ZROW;
    float4 fa = h4_to_f4(va);
    float4 fb = h4_to_f4(vb);
    acc.x += fa.x + fb.x;
    acc.y += fa.y + fb.y;
    acc.z += fa.z + fb.z;
    acc.w += fa.w + fb.w;
    s0 = t0;
    s1 = t1;
  }
  if (i < nch) {
    float4 fa = h4_to_f4(hs4[s0 * 8 + sub]);
    acc.x += fa.x; acc.y += fa.y; acc.z += fa.z; acc.w += fa.w;
  }
  // reduce across the 8 edge-slot groups (stride 8,16,32 in lane id)
#pragma unroll
  for (int m = 8; m < 64; m <<= 1) {
    acc.x += __shfl_xor(acc.x, m);
    acc.y += __shfl_xor(acc.y, m);
    acc.z += __shfl_xor(acc.z, m);
    acc.w += __shfl_xor(acc.w, m);
  }
  // self-loop (hs already dis-scaled); added post-reduction => counted once
  float4 sf = h4_to_f4(hs4[n * 8 + sub]);
  acc.x += sf.x; acc.y += sf.y; acc.z += sf.z; acc.w += sf.w;
  return acc;
}

__global__ __launch_bounds__(256) void k_agg1(const u16* __restrict__ hs,
                                              const int* __restrict__ row_ptr,
                                              const int* __restrict__ col,
                                              const float* __restrict__ dis,
                                              const float* __restrict__ b,
                                              u16* __restrict__ out) {
  int t = threadIdx.x;
  int n = blockIdx.x * 4 + (t >> 6);
  int l = t & 63;
  int g = (l >> 3), sub = l & 7;
  float4 acc = agg_row_wide(hs, row_ptr, col, n, g, sub);
  if (g == 0) {
    float d = dis[n];
    float4 bq = ((const float4*)b)[sub];
    float4 o;
    o.x = fmaxf(fmaf(acc.x, d, bq.x), 0.f);
    o.y = fmaxf(fmaf(acc.y, d, bq.y), 0.f);
    o.z = fmaxf(fmaf(acc.z, d, bq.z), 0.f);
    o.w = fmaxf(fmaf(acc.w, d, bq.w), 0.f);
    ((ushort4*)(out + (size_t)n * EMB))[sub] = f4_to_h4(o);
  }
}

__global__ __launch_bounds__(256) void k_agg2pool(const u16* __restrict__ hs,
                                                  const int* __restrict__ row_ptr,
                                                  const int* __restrict__ col,
                                                  const float* __restrict__ dis,
                                                  const float* __restrict__ b2,
                                                  const float* __restrict__ Wo,
                                                  const int* __restrict__ batch,
                                                  float* __restrict__ gacc) {
  int t = threadIdx.x;
  int n = blockIdx.x * 4 + (t >> 6);
  int l = t & 63;
  int g = (l >> 3), sub = l & 7;
  float4 acc = agg_row_wide(hs, row_ptr, col, n, g, sub);
  float d = dis[n];
  float4 bq = ((const float4*)b2)[sub];
  float4 wq = ((const float4*)Wo)[sub];
  float p = fmaxf(fmaf(acc.x, d, bq.x), 0.f) * wq.x
          + fmaxf(fmaf(acc.y, d, bq.y), 0.f) * wq.y
          + fmaxf(fmaf(acc.z, d, bq.z), 0.f) * wq.z
          + fmaxf(fmaf(acc.w, d, bq.w), 0.f) * wq.w;
  // reduce over sub=0..7 (all g-groups hold identical values)
  p += __shfl_xor(p, 1);
  p += __shfl_xor(p, 2);
  p += __shfl_xor(p, 4);
  if (l == 0) atomicAdd(&gacc[batch[n]], p);
}

__global__ void k_finalize(const float* __restrict__ gacc, const int* __restrict__ gcnt,
                           const float* __restrict__ bo, float* __restrict__ out) {
  int g = blockIdx.x * 256 + threadIdx.x;
  if (g < N_GRAPHS) out[g] = gacc[g] / fmaxf((float)gcnt[g], 1.0f) + bo[0];
}

// ---------------- launch ----------------

extern "C" void kernel_launch(void* const* d_in, const int* in_sizes, int n_in,
                              void* d_out, int out_size, void* d_ws, size_t ws_size,
                              hipStream_t stream) {
  const float* x     = (const float*)d_in[0];
  const int*   ei    = (const int*)d_in[1];   // [2, E]: src then dst
  const int*   batch = (const int*)d_in[2];
  const float* W1    = (const float*)d_in[3];
  const float* b1    = (const float*)d_in[4];
  const float* W2    = (const float*)d_in[5];
  const float* b2    = (const float*)d_in[6];
  const float* Wo    = (const float*)d_in[7];
  const float* bo    = (const float*)d_in[8];
  float* out = (float*)d_out;

  const int* src = ei;
  const int* dst = ei + N_EDGES;

  char* w = (char*)d_ws;
  int*   degcnt  = (int*)w;    w += (size_t)N_NODES * 4;       // zeroed
  int*   cursor  = (int*)w;    w += (size_t)N_NODES * 4;       // zeroed
  float* gacc    = (float*)w;  w += (size_t)N_GRAPHS * 4;      // zeroed
  int*   gcnt    = (int*)w;    w += (size_t)N_GRAPHS * 4;      // zeroed
  size_t zero_bytes = (size_t)(w - (char*)d_ws);
  int*   row_ptr = (int*)w;    w += (size_t)(N_NODES + 4) * 4;
  int*   blocksum= (int*)w;    w += 128 * 4;
  int*   blockoff= (int*)w;    w += 128 * 4;
  int*   col     = (int*)w;    w += (size_t)PADCAP * 4;
  float* dis     = (float*)w;  w += (size_t)N_NODES * 4;
  u16*   hs1     = (u16*)w;    w += (size_t)(N_NODES + 1) * EMB * 2;  // +1 zero row
  u16*   out1    = (u16*)w;    w += (size_t)N_NODES * EMB * 2;
  u16*   hs2     = hs1;  // hs1 dead after agg1; zero row persists

  const int EB = (N_EDGES + 255) / 256;    // 6250
  const int NB = (N_NODES + 255) / 256;    // 391
  const int SB = (N_NODES + 1023) / 1024;  // 98
  const int RB = N_NODES / 8;              // 12500 (exact)
  const int AB = N_NODES / 4;              // 25000 wave-per-node blocks
  const int CB = (PADCAP + 255) / 256;

  hipMemsetAsync(d_ws, 0, zero_bytes, stream);

  k_hist<<<EB, 256, 0, stream>>>(dst, degcnt);
  k_node_init<<<NB, 256, 0, stream>>>(degcnt, batch, dis, gcnt);
  k_colfill<<<CB, 256, 0, stream>>>(col, hs1);
  k_scanA<<<SB, 256, 0, stream>>>(degcnt, blocksum);
  k_scanB<<<1, 64, 0, stream>>>(blocksum, blockoff, row_ptr + N_NODES, SB);
  k_scanC<<<SB, 256, 0, stream>>>(degcnt, blockoff, row_ptr);
  k_fill<<<EB, 256, 0, stream>>>(src, dst, row_ptr, cursor, col);

  k_gemm1<<<RB, 256, 0, stream>>>(x, W1, dis, hs1);
  k_agg1<<<AB, 256, 0, stream>>>(hs1, row_ptr, col, dis, b1, out1);
  k_gemm2<<<RB, 256, 0, stream>>>(out1, W2, dis, hs2);
  k_agg2pool<<<AB, 256, 0, stream>>>(hs2, row_ptr, col, dis, b2, Wo, batch, gacc);
  k_finalize<<<2, 256, 0, stream>>>(gacc, gcnt, bo, out);
}